// Round 14
// baseline (186.400 us; speedup 1.0000x reference)
//
#include <hip/hip_runtime.h>
#include <stdint.h>

typedef __attribute__((ext_vector_type(8))) _Float16 half8v;
typedef __attribute__((ext_vector_type(16))) float float16v;
typedef __attribute__((ext_vector_type(4))) float float4v;

#define NPTS_WG 32

// LDS act layout: [c][granule g = j>>3][p 32][8 u16]  (granule-major, no swizzle)
// u16 index:
__device__ __forceinline__ int agp(int c, int g, int p) {
    return ((c * 32 + g) * 32 + p) * 8;
}

__device__ __forceinline__ unsigned short f16b(float x) {
    const _Float16 h = (_Float16)x;            // RN, 11-bit mantissa
    return __builtin_bit_cast(unsigned short, h);
}

__device__ __forceinline__ uint32_t pk2f16(float a, float b) {
    return (uint32_t)f16b(a) | ((uint32_t)f16b(b) << 16);
}

__device__ __forceinline__ float fast_tanh(float z) {
    const float e = __expf(2.0f * z);          // ~2 ulp
    return 1.0f - 2.0f / (e + 1.0f);           // exact saturation
}

// ---- precompute: transpose + f16 hi/lo split W1..W3 into d_ws ----
// wt layout: [L][{hi,lo}][j][k] ushort(f16 bits); hi at L*131072 + j*256 + k, lo +65536
__global__ void wt_split_kernel(const float* __restrict__ W1, const float* __restrict__ W2,
                                const float* __restrict__ W3, unsigned short* __restrict__ wt)
{
    const int b = blockIdx.x;            // 48 blocks: 3 layers x 16 k-strips
    const int L = b >> 4;
    const int k0 = (b & 15) * 16;
    const float* W = (L == 0) ? W1 : (L == 1) ? W2 : W3;
    const int j = threadIdx.x;           // 0..255
    uint32_t hi[16], lo[16];
#pragma unroll
    for (int e = 0; e < 16; ++e) {
        const float x = W[(k0 + e) * 256 + j];     // coalesced: lanes = consecutive j
        const unsigned short h = f16b(x);
        const float hf = (float)__builtin_bit_cast(_Float16, h);
        hi[e] = h;
        lo[e] = f16b(x - hf);
    }
    unsigned short* dh = wt + (size_t)L * 131072 + j * 256 + k0;
    unsigned short* dl = dh + 65536;
    uint4 h0 = make_uint4(hi[0] | (hi[1] << 16), hi[2] | (hi[3] << 16),
                          hi[4] | (hi[5] << 16), hi[6] | (hi[7] << 16));
    uint4 h1 = make_uint4(hi[8] | (hi[9] << 16), hi[10] | (hi[11] << 16),
                          hi[12] | (hi[13] << 16), hi[14] | (hi[15] << 16));
    uint4 l0 = make_uint4(lo[0] | (lo[1] << 16), lo[2] | (lo[3] << 16),
                          lo[4] | (lo[5] << 16), lo[6] | (lo[7] << 16));
    uint4 l1 = make_uint4(lo[8] | (lo[9] << 16), lo[10] | (lo[11] << 16),
                          lo[12] | (lo[13] << 16), lo[14] | (lo[15] << 16));
    ((uint4*)dh)[0] = h0; ((uint4*)dh)[1] = h1;
    ((uint4*)dl)[0] = l0; ((uint4*)dl)[1] = l1;
}

// ---- main kernel: 512 threads (8 waves), 32 points/WG, 32x32x16 MFMA ----
__global__ __launch_bounds__(512, 2)
void pinn_mfma(const float* __restrict__ x_norm, const float* __restrict__ nu,
               const float* __restrict__ x_std, const float* __restrict__ y_std,
               const float* __restrict__ W0, const float* __restrict__ b0,
               const float* __restrict__ b1, const float* __restrict__ b2,
               const float* __restrict__ b3, const float* __restrict__ W4,
               const unsigned short* __restrict__ wt, float* __restrict__ out)
{
    __shared__ unsigned short AH[7 * 32 * 256]; // 114688 B f16 activations
    __shared__ float w4_lds[256 * 4];           // 4 KB
    __shared__ float part_lds[8 * 6 * 32 * 4];  // 24 KB split-K partials
    __shared__ float y_lds[24 * 32];            // 3 KB

    const int tid = threadIdx.x;
    const int lane = tid & 63;
    const int wv = tid >> 6;     // wave 0..7
    const int l31 = lane & 31;
    const int hh = lane >> 5;    // 0..1 (k-half selector for 32x32 fragments)
    const int base_pt = blockIdx.x * NPTS_WG;

    if (tid < 256) ((float4*)w4_lds)[tid] = ((const float4*)W4)[tid];

    // ---- layer 0: 3 -> 256 dual seed. p = tid&31 -> conflict-free granule writes
    {
        const int p = tid & 31;            // 0..31 (varies per lane)
        const int jq = tid >> 5;           // 0..15 (wave-uniform-ish: broadcast W0)
        const float x0 = x_norm[(base_pt + p) * 3 + 0];
        const float x1 = x_norm[(base_pt + p) * 3 + 1];
        const float x2 = x_norm[(base_pt + p) * 3 + 2];
#pragma unroll
        for (int hf = 0; hf < 2; ++hf) {
            const int j8 = jq * 16 + hf * 8;
            const int g = 2 * jq + hf;
            float w0r[8], w1r[8], w2r[8], b0r[8];
            *(float4*)&w0r[0] = *(const float4*)&W0[0 * 256 + j8];
            *(float4*)&w0r[4] = *(const float4*)&W0[0 * 256 + j8 + 4];
            *(float4*)&w1r[0] = *(const float4*)&W0[1 * 256 + j8];
            *(float4*)&w1r[4] = *(const float4*)&W0[1 * 256 + j8 + 4];
            *(float4*)&w2r[0] = *(const float4*)&W0[2 * 256 + j8];
            *(float4*)&w2r[4] = *(const float4*)&W0[2 * 256 + j8 + 4];
            *(float4*)&b0r[0] = *(const float4*)&b0[j8];
            *(float4*)&b0r[4] = *(const float4*)&b0[j8 + 4];
            union { unsigned short u[8]; half8v v; } hv[7];
#pragma unroll
            for (int e = 0; e < 8; ++e) {
                const float z = b0r[e] + x0 * w0r[e] + x1 * w1r[e] + x2 * w2r[e];
                const float t = fast_tanh(z);
                const float s = 1.f - t * t;
                hv[0].u[e] = f16b(t);
                const float wvv[3] = {w0r[e], w1r[e], w2r[e]};
#pragma unroll
                for (int i = 0; i < 3; ++i) {
                    hv[1 + i].u[e] = f16b(s * wvv[i]);
                    hv[4 + i].u[e] = f16b(-2.f * t * s * wvv[i] * wvv[i]);
                }
            }
#pragma unroll
            for (int c = 0; c < 7; ++c)
                *(half8v*)&AH[agp(c, g, p)] = hv[c].v;  // stride-16B across lanes
        }
    }
    __syncthreads();

    // ---- layers 1..3: D[j' 32][p 32] = W x A via mfma_32x32x16 ----
    // A-op (W): lane row j' = wv*32 + l31, k = ch*16 + 8*hh + e  (wt row-major)
    // B-op (act): lane col p = l31, k(j) granule g = 2*ch + hh    (LDS granule-major)
    const float* biases[3] = {b1, b2, b3};
    const int jrow = (wv * 32 + l31) * 256;
    const int kofs = 8 * hh;

#pragma unroll 1
    for (int L = 0; L < 3; ++L) {
        const unsigned short* wtL = wt + (size_t)L * 131072;
        float16v acc[7];
#pragma unroll
        for (int c = 0; c < 7; ++c)
#pragma unroll
            for (int e = 0; e < 16; ++e) acc[c][e] = 0.f;

        // prologue: chunk 0 fragments  (act granule g = hh)
        half8v wh = *(const half8v*)(wtL + jrow + kofs);
        half8v wl = *(const half8v*)(wtL + 65536 + jrow + kofs);
        half8v a[7];
#pragma unroll
        for (int c = 0; c < 7; ++c)
            a[c] = *(const half8v*)&AH[agp(c, hh, l31)];

#pragma unroll
        for (int ch = 0; ch < 16; ++ch) {
            half8v nwh, nwl, na[7];
            if (ch < 15) {   // depth-1 prefetch of chunk+1 (W global + A LDS)
                const int nk = (ch + 1) * 16 + kofs;
                const int ng = 2 * (ch + 1) + hh;
                nwh = *(const half8v*)(wtL + jrow + nk);
                nwl = *(const half8v*)(wtL + 65536 + jrow + nk);
#pragma unroll
                for (int c = 0; c < 7; ++c)
                    na[c] = *(const half8v*)&AH[agp(c, ng, l31)];
            }
            __builtin_amdgcn_s_setprio(1);
#pragma unroll
            for (int c = 0; c < 7; ++c) {
                acc[c] = __builtin_amdgcn_mfma_f32_32x32x16_f16(wh, a[c], acc[c], 0, 0, 0);
                if (c < 4)   // d2 channels (4..6): hi-product only (nu-damped 100x)
                    acc[c] = __builtin_amdgcn_mfma_f32_32x32x16_f16(wl, a[c], acc[c], 0, 0, 0);
            }
            __builtin_amdgcn_s_setprio(0);
            if (ch < 15) {
                wh = nwh; wl = nwl;
#pragma unroll
                for (int c = 0; c < 7; ++c) a[c] = na[c];
            }
        }

        const float* bL = biases[L];
        __syncthreads();   // all reads of AH done before overwrite
        // D rows: j' = wv*32 + (reg&3) + 8*(reg>>2) + 4*hh, col p = l31
#pragma unroll
        for (int q = 0; q < 4; ++q) {
            const int j0 = wv * 32 + 8 * q + 4 * hh;   // 4-aligned row base
            const int g = wv * 4 + q;                  // granule of j0 (j0>>3)
            float bj[4];
            *(float4*)&bj[0] = *(const float4*)&bL[j0];
            float val[7][4];
#pragma unroll
            for (int r = 0; r < 4; ++r) {
                const int e = q * 4 + r;
                const float z = acc[0][e] + bj[r];
                const float t = fast_tanh(z);
                const float s = 1.f - t * t;
                val[0][r] = t;
#pragma unroll
                for (int i = 0; i < 3; ++i) {
                    const float d1 = acc[1 + i][e];
                    const float d2 = acc[4 + i][e];
                    val[1 + i][r] = s * d1;
                    val[4 + i][r] = s * d2 - 2.f * t * s * d1 * d1;
                }
            }
#pragma unroll
            for (int c = 0; c < 7; ++c) {
                const uint32_t u0 = pk2f16(val[c][0], val[c][1]);
                const uint32_t u1 = pk2f16(val[c][2], val[c][3]);
                // elems 4*hh..4*hh+3 of granule g at point l31: 8B write
                *(uint2*)&AH[agp(c, g, l31) + 4 * hh] = make_uint2(u0, u1);
            }
        }
        __syncthreads();
    }

    // ---- layer 4: 256 -> 4, split-K across 8 waves, 16x16x32, two p-halves ----
    {
        const int l15 = lane & 15;
        const int g4 = lane >> 4;
        const int koct = wv * 32 + 8 * g4;     // j index into act planes
        const int gr = wv * 4 + g4;            // its granule
        union { uint32_t u[4]; half8v v; } HB, LB;
#pragma unroll
        for (int i = 0; i < 4; ++i) {
            const float w0v = (l15 < 4) ? w4_lds[(koct + 2 * i) * 4 + l15] : 0.f;
            const float w1v = (l15 < 4) ? w4_lds[(koct + 2 * i + 1) * 4 + l15] : 0.f;
            const unsigned short h0 = f16b(w0v), h1 = f16b(w1v);
            const float r0 = w0v - (float)__builtin_bit_cast(_Float16, h0);
            const float r1 = w1v - (float)__builtin_bit_cast(_Float16, h1);
            HB.u[i] = (uint32_t)h0 | ((uint32_t)h1 << 16);
            LB.u[i] = (uint32_t)f16b(r0) | ((uint32_t)f16b(r1) << 16);
        }
        float4v acc4[6][2];
#pragma unroll
        for (int c = 0; c < 6; ++c)
#pragma unroll
            for (int ph = 0; ph < 2; ++ph) acc4[c][ph] = (float4v){0.f, 0.f, 0.f, 0.f};
#pragma unroll
        for (int c = 0; c < 6; ++c) {
#pragma unroll
            for (int ph = 0; ph < 2; ++ph) {
                const half8v ah = *(const half8v*)&AH[agp(1 + c, gr, l15 + 16 * ph)];
                acc4[c][ph] = __builtin_amdgcn_mfma_f32_16x16x32_f16(HB.v, ah, acc4[c][ph], 0, 0, 0);
                if (c < 3)
                    acc4[c][ph] = __builtin_amdgcn_mfma_f32_16x16x32_f16(LB.v, ah, acc4[c][ph], 0, 0, 0);
            }
        }
        if (g4 == 0) {   // rows 0..3 = outputs u,v,w,p for point l15 + 16*ph
#pragma unroll
            for (int c = 0; c < 6; ++c)
#pragma unroll
                for (int ph = 0; ph < 2; ++ph)
                    *(float4*)&part_lds[((wv * 6 + c) * 32 + ph * 16 + l15) * 4] =
                        make_float4(acc4[c][ph][0], acc4[c][ph][1],
                                    acc4[c][ph][2], acc4[c][ph][3]);
        }
    }
    __syncthreads();

    {          // reduce split-K partials + de-normalization scale (24 x 32 items)
        const int p = tid & 31;
#pragma unroll
        for (int co = tid >> 5; co < 24; co += 16) {
            const int o = co & 3;
            const int c6 = co >> 2;       // 0..5: 0-2 = d1_i, 3-5 = d2_i
            float sum = 0.f;
#pragma unroll
            for (int w8 = 0; w8 < 8; ++w8)
                sum += part_lds[((w8 * 6 + c6) * 32 + p) * 4 + o];
            const int i = (c6 < 3) ? c6 : (c6 - 3);
            const float xs = x_std[i];
            const float scale = y_std[o] / ((c6 < 3) ? xs : (xs * xs));
            y_lds[co * 32 + p] = sum * scale;
        }
    }
    __syncthreads();

    if (tid < 32) {           // physics loss per point
        const int p = tid;
        const float nuv = nu[0];
        #define YV(c6, o) y_lds[(((c6) * 4) + (o)) * 32 + p]
        const float cont = YV(0, 0) + YV(1, 1) + YV(2, 2);
        const float lap0 = YV(3, 0) + YV(4, 0) + YV(5, 0);
        const float lap1 = YV(3, 1) + YV(4, 1) + YV(5, 1);
        const float lap2 = YV(3, 2) + YV(4, 2) + YV(5, 2);
        const float mx = YV(0, 3) - nuv * lap0;
        const float my = YV(1, 3) - nuv * lap1;
        const float mz = YV(2, 3) - nuv * lap2;
        out[base_pt + p] = cont * cont + mx * mx + my * my + mz * mz;
        #undef YV
    }
}

extern "C" void kernel_launch(void* const* d_in, const int* in_sizes, int n_in,
                              void* d_out, int out_size, void* d_ws, size_t ws_size,
                              hipStream_t stream)
{
    const float* x_norm = (const float*)d_in[0];
    const float* nu     = (const float*)d_in[1];
    const float* x_std  = (const float*)d_in[2];
    const float* y_std  = (const float*)d_in[3];
    const float* W0 = (const float*)d_in[4];  const float* b0 = (const float*)d_in[5];
    const float* W1 = (const float*)d_in[6];  const float* b1 = (const float*)d_in[7];
    const float* W2 = (const float*)d_in[8];  const float* b2 = (const float*)d_in[9];
    const float* W3 = (const float*)d_in[10]; const float* b3 = (const float*)d_in[11];
    const float* W4 = (const float*)d_in[12];
    (void)n_in; (void)out_size; (void)ws_size;
    unsigned short* wt = (unsigned short*)d_ws;   // 786432 B
    float* out = (float*)d_out;
    const int npts = in_sizes[0] / 3;

    wt_split_kernel<<<48, 256, 0, stream>>>(W1, W2, W3, wt);
    pinn_mfma<<<npts / NPTS_WG, 512, 0, stream>>>(x_norm, nu, x_std, y_std,
        W0, b0, b1, b2, b3, W4, wt, out);
}

// Round 15
// 171.981 us; speedup vs baseline: 1.0838x; 1.0838x over previous
//
#include <hip/hip_runtime.h>
#include <stdint.h>

typedef __attribute__((ext_vector_type(8))) _Float16 half8v;
typedef __attribute__((ext_vector_type(16))) float float16v;
typedef __attribute__((ext_vector_type(4))) float float4v;

#define NPTS_WG 32

// LDS act layout: [c][granule g = j>>3][p 32][8 u16]  (granule-major)
__device__ __forceinline__ int agp(int c, int g, int p) {
    return ((c * 32 + g) * 32 + p) * 8;
}

__device__ __forceinline__ unsigned short f16b(float x) {
    const _Float16 h = (_Float16)x;            // RN, 11-bit mantissa
    return __builtin_bit_cast(unsigned short, h);
}

__device__ __forceinline__ uint32_t pk2f16(float a, float b) {
    return (uint32_t)f16b(a) | ((uint32_t)f16b(b) << 16);
}

__device__ __forceinline__ float fast_tanh(float z) {
    const float e = __expf(2.0f * z);          // ~2 ulp
    return 1.0f - 2.0f / (e + 1.0f);           // exact saturation
}

// ---- precompute: W1..W3 -> fragment-order hi/lo f16 blocks in d_ws ----
// Block (L, part, wv, ch) = 64 lanes x 8 u16 (16B) = 1KB, contiguous.
// Lane l = hh*32 + l31 holds W[k = ch*16 + 8*hh + e][j = wv*32 + l31].
__global__ void wt_split_kernel(const float* __restrict__ W1, const float* __restrict__ W2,
                                const float* __restrict__ W3, unsigned short* __restrict__ wt)
{
    const int b = blockIdx.x;            // 48 blocks: 3 layers x 16 k-strips
    const int L = b >> 4;
    const int ch = b & 15;               // chunk = k>>4
    const int k0 = ch * 16;
    const float* W = (L == 0) ? W1 : (L == 1) ? W2 : W3;
    const int j = threadIdx.x;           // 0..255
    const int wv = j >> 5, l31 = j & 31;
    uint32_t hi[16], lo[16];
#pragma unroll
    for (int e = 0; e < 16; ++e) {
        const float x = W[(k0 + e) * 256 + j];     // coalesced: lanes = consecutive j
        const unsigned short h = f16b(x);
        const float hf = (float)__builtin_bit_cast(_Float16, h);
        hi[e] = h;
        lo[e] = f16b(x - hf);
    }
    // dest u16 index: ((((L*2+part)*8 + wv)*16 + ch)*64 + hh*32 + l31)*8 + e&7
#pragma unroll
    for (int part = 0; part < 2; ++part) {
        const uint32_t* src = part ? lo : hi;
        unsigned short* base = wt +
            ((((size_t)(L * 2 + part) * 8 + wv) * 16 + ch) * 64) * 8;
#pragma unroll
        for (int hh = 0; hh < 2; ++hh) {
            uint4 v;
            const uint32_t* s = src + hh * 8;
            v.x = s[0] | (s[1] << 16);
            v.y = s[2] | (s[3] << 16);
            v.z = s[4] | (s[5] << 16);
            v.w = s[6] | (s[7] << 16);
            *(uint4*)(base + (hh * 32 + l31) * 8) = v;
        }
    }
}

// ---- main kernel: 512 threads (8 waves), 32 points/WG, 32x32x16 MFMA ----
__global__ __launch_bounds__(512, 2)
void pinn_mfma(const float* __restrict__ x_norm, const float* __restrict__ nu,
               const float* __restrict__ x_std, const float* __restrict__ y_std,
               const float* __restrict__ W0, const float* __restrict__ b0,
               const float* __restrict__ b1, const float* __restrict__ b2,
               const float* __restrict__ b3, const float* __restrict__ W4,
               const unsigned short* __restrict__ wt, float* __restrict__ out)
{
    __shared__ unsigned short AH[7 * 32 * 256]; // 114688 B f16 activations
    __shared__ float w4_lds[256 * 4];           // 4 KB
    __shared__ float part_lds[8 * 6 * 32 * 4];  // 24 KB split-K partials
    __shared__ float y_lds[24 * 32];            // 3 KB

    const int tid = threadIdx.x;
    const int lane = tid & 63;
    const int wv = tid >> 6;     // wave 0..7
    const int l31 = lane & 31;
    const int hh = lane >> 5;    // 0..1 (k-half selector for 32x32 fragments)
    const int base_pt = blockIdx.x * NPTS_WG;

    if (tid < 256) ((float4*)w4_lds)[tid] = ((const float4*)W4)[tid];

    // ---- layer 0: 3 -> 256 dual seed. p = tid&31 -> conflict-free granule writes
    {
        const int p = tid & 31;            // 0..31 (varies per lane)
        const int jq = tid >> 5;           // 0..15
        const float x0 = x_norm[(base_pt + p) * 3 + 0];
        const float x1 = x_norm[(base_pt + p) * 3 + 1];
        const float x2 = x_norm[(base_pt + p) * 3 + 2];
#pragma unroll
        for (int hf = 0; hf < 2; ++hf) {
            const int j8 = jq * 16 + hf * 8;
            const int g = 2 * jq + hf;
            float w0r[8], w1r[8], w2r[8], b0r[8];
            *(float4*)&w0r[0] = *(const float4*)&W0[0 * 256 + j8];
            *(float4*)&w0r[4] = *(const float4*)&W0[0 * 256 + j8 + 4];
            *(float4*)&w1r[0] = *(const float4*)&W0[1 * 256 + j8];
            *(float4*)&w1r[4] = *(const float4*)&W0[1 * 256 + j8 + 4];
            *(float4*)&w2r[0] = *(const float4*)&W0[2 * 256 + j8];
            *(float4*)&w2r[4] = *(const float4*)&W0[2 * 256 + j8 + 4];
            *(float4*)&b0r[0] = *(const float4*)&b0[j8];
            *(float4*)&b0r[4] = *(const float4*)&b0[j8 + 4];
            union { unsigned short u[8]; half8v v; } hv[7];
#pragma unroll
            for (int e = 0; e < 8; ++e) {
                const float z = b0r[e] + x0 * w0r[e] + x1 * w1r[e] + x2 * w2r[e];
                const float t = fast_tanh(z);
                const float s = 1.f - t * t;
                hv[0].u[e] = f16b(t);
                const float wvv[3] = {w0r[e], w1r[e], w2r[e]};
#pragma unroll
                for (int i = 0; i < 3; ++i) {
                    hv[1 + i].u[e] = f16b(s * wvv[i]);
                    hv[4 + i].u[e] = f16b(-2.f * t * s * wvv[i] * wvv[i]);
                }
            }
#pragma unroll
            for (int c = 0; c < 7; ++c)
                *(half8v*)&AH[agp(c, g, p)] = hv[c].v;  // stride-16B across lanes
        }
    }
    __syncthreads();

    // ---- layers 1..3: D[j' 32][p 32] = W x A via mfma_32x32x16 ----
    // W fragments: contiguous 1KB blocks, per-lane offset lane*16B, +1KB/chunk.
    const float* biases[3] = {b1, b2, b3};
    const int laneq = lane * 8;

#pragma unroll 1
    for (int L = 0; L < 3; ++L) {
        const unsigned short* whb = wt + (((size_t)(L * 2 + 0) * 8 + wv) * 16) * 512 + laneq;
        const unsigned short* wlb = wt + (((size_t)(L * 2 + 1) * 8 + wv) * 16) * 512 + laneq;
        float16v acc[7];
#pragma unroll
        for (int c = 0; c < 7; ++c)
#pragma unroll
            for (int e = 0; e < 16; ++e) acc[c][e] = 0.f;

        // prologue: W chunks 0,1 (3-buffer), A chunk 0
        half8v wh[3], wl[3], a[7], na[7];
        wh[0] = *(const half8v*)(whb);
        wl[0] = *(const half8v*)(wlb);
        wh[1] = *(const half8v*)(whb + 512);
        wl[1] = *(const half8v*)(wlb + 512);
#pragma unroll
        for (int c = 0; c < 7; ++c)
            a[c] = *(const half8v*)&AH[agp(c, hh, l31)];

#pragma unroll
        for (int ch = 0; ch < 16; ++ch) {
            if (ch < 14) {   // depth-2 W prefetch (coalesced 1KB block)
                wh[(ch + 2) % 3] = *(const half8v*)(whb + (ch + 2) * 512);
                wl[(ch + 2) % 3] = *(const half8v*)(wlb + (ch + 2) * 512);
            }
            if (ch < 15) {   // depth-1 A prefetch (LDS)
                const int ng = 2 * (ch + 1) + hh;
#pragma unroll
                for (int c = 0; c < 7; ++c)
                    na[c] = *(const half8v*)&AH[agp(c, ng, l31)];
            }
            __builtin_amdgcn_s_setprio(1);
#pragma unroll
            for (int c = 0; c < 7; ++c) {
                acc[c] = __builtin_amdgcn_mfma_f32_32x32x16_f16(wh[ch % 3], a[c], acc[c], 0, 0, 0);
                if (c < 4)   // d2 channels (4..6): hi-product only (nu-damped 100x)
                    acc[c] = __builtin_amdgcn_mfma_f32_32x32x16_f16(wl[ch % 3], a[c], acc[c], 0, 0, 0);
            }
            __builtin_amdgcn_s_setprio(0);
            if (ch < 15) {
#pragma unroll
                for (int c = 0; c < 7; ++c) a[c] = na[c];
            }
        }

        const float* bL = biases[L];
        __syncthreads();   // all reads of AH done before overwrite
        // D rows: j' = wv*32 + (reg&3) + 8*(reg>>2) + 4*hh, col p = l31
#pragma unroll
        for (int q = 0; q < 4; ++q) {
            const int j0 = wv * 32 + 8 * q + 4 * hh;   // 4-aligned row base
            const int g = wv * 4 + q;                  // granule of j0 (j0>>3)
            float bj[4];
            *(float4*)&bj[0] = *(const float4*)&bL[j0];
            float val[7][4];
#pragma unroll
            for (int r = 0; r < 4; ++r) {
                const int e = q * 4 + r;
                const float z = acc[0][e] + bj[r];
                const float t = fast_tanh(z);
                const float s = 1.f - t * t;
                val[0][r] = t;
#pragma unroll
                for (int i = 0; i < 3; ++i) {
                    const float d1 = acc[1 + i][e];
                    const float d2 = acc[4 + i][e];
                    val[1 + i][r] = s * d1;
                    val[4 + i][r] = s * d2 - 2.f * t * s * d1 * d1;
                }
            }
#pragma unroll
            for (int c = 0; c < 7; ++c) {
                const uint32_t u0 = pk2f16(val[c][0], val[c][1]);
                const uint32_t u1 = pk2f16(val[c][2], val[c][3]);
                *(uint2*)&AH[agp(c, g, l31) + 4 * hh] = make_uint2(u0, u1);
            }
        }
        __syncthreads();
    }

    // ---- layer 4: 256 -> 4, split-K across 8 waves, 16x16x32, two p-halves ----
    {
        const int l15 = lane & 15;
        const int g4 = lane >> 4;
        const int koct = wv * 32 + 8 * g4;     // j index into act planes
        const int gr = wv * 4 + g4;            // its granule
        union { uint32_t u[4]; half8v v; } HB, LB;
#pragma unroll
        for (int i = 0; i < 4; ++i) {
            const float w0v = (l15 < 4) ? w4_lds[(koct + 2 * i) * 4 + l15] : 0.f;
            const float w1v = (l15 < 4) ? w4_lds[(koct + 2 * i + 1) * 4 + l15] : 0.f;
            const unsigned short h0 = f16b(w0v), h1 = f16b(w1v);
            const float r0 = w0v - (float)__builtin_bit_cast(_Float16, h0);
            const float r1 = w1v - (float)__builtin_bit_cast(_Float16, h1);
            HB.u[i] = (uint32_t)h0 | ((uint32_t)h1 << 16);
            LB.u[i] = (uint32_t)f16b(r0) | ((uint32_t)f16b(r1) << 16);
        }
        float4v acc4[6][2];
#pragma unroll
        for (int c = 0; c < 6; ++c)
#pragma unroll
            for (int ph = 0; ph < 2; ++ph) acc4[c][ph] = (float4v){0.f, 0.f, 0.f, 0.f};
#pragma unroll
        for (int c = 0; c < 6; ++c) {
#pragma unroll
            for (int ph = 0; ph < 2; ++ph) {
                const half8v ah = *(const half8v*)&AH[agp(1 + c, gr, l15 + 16 * ph)];
                acc4[c][ph] = __builtin_amdgcn_mfma_f32_16x16x32_f16(HB.v, ah, acc4[c][ph], 0, 0, 0);
                if (c < 3)
                    acc4[c][ph] = __builtin_amdgcn_mfma_f32_16x16x32_f16(LB.v, ah, acc4[c][ph], 0, 0, 0);
            }
        }
        if (g4 == 0) {   // rows 0..3 = outputs u,v,w,p for point l15 + 16*ph
#pragma unroll
            for (int c = 0; c < 6; ++c)
#pragma unroll
                for (int ph = 0; ph < 2; ++ph)
                    *(float4*)&part_lds[((wv * 6 + c) * 32 + ph * 16 + l15) * 4] =
                        make_float4(acc4[c][ph][0], acc4[c][ph][1],
                                    acc4[c][ph][2], acc4[c][ph][3]);
        }
    }
    __syncthreads();

    {          // reduce split-K partials + de-normalization scale (24 x 32 items)
        const int p = tid & 31;
#pragma unroll
        for (int co = tid >> 5; co < 24; co += 16) {
            const int o = co & 3;
            const int c6 = co >> 2;       // 0..5: 0-2 = d1_i, 3-5 = d2_i
            float sum = 0.f;
#pragma unroll
            for (int w8 = 0; w8 < 8; ++w8)
                sum += part_lds[((w8 * 6 + c6) * 32 + p) * 4 + o];
            const int i = (c6 < 3) ? c6 : (c6 - 3);
            const float xs = x_std[i];
            const float scale = y_std[o] / ((c6 < 3) ? xs : (xs * xs));
            y_lds[co * 32 + p] = sum * scale;
        }
    }
    __syncthreads();

    if (tid < 32) {           // physics loss per point
        const int p = tid;
        const float nuv = nu[0];
        #define YV(c6, o) y_lds[(((c6) * 4) + (o)) * 32 + p]
        const float cont = YV(0, 0) + YV(1, 1) + YV(2, 2);
        const float lap0 = YV(3, 0) + YV(4, 0) + YV(5, 0);
        const float lap1 = YV(3, 1) + YV(4, 1) + YV(5, 1);
        const float lap2 = YV(3, 2) + YV(4, 2) + YV(5, 2);
        const float mx = YV(0, 3) - nuv * lap0;
        const float my = YV(1, 3) - nuv * lap1;
        const float mz = YV(2, 3) - nuv * lap2;
        out[base_pt + p] = cont * cont + mx * mx + my * my + mz * mz;
        #undef YV
    }
}

extern "C" void kernel_launch(void* const* d_in, const int* in_sizes, int n_in,
                              void* d_out, int out_size, void* d_ws, size_t ws_size,
                              hipStream_t stream)
{
    const float* x_norm = (const float*)d_in[0];
    const float* nu     = (const float*)d_in[1];
    const float* x_std  = (const float*)d_in[2];
    const float* y_std  = (const float*)d_in[3];
    const float* W0 = (const float*)d_in[4];  const float* b0 = (const float*)d_in[5];
    const float* W1 = (const float*)d_in[6];  const float* b1 = (const float*)d_in[7];
    const float* W2 = (const float*)d_in[8];  const float* b2 = (const float*)d_in[9];
    const float* W3 = (const float*)d_in[10]; const float* b3 = (const float*)d_in[11];
    const float* W4 = (const float*)d_in[12];
    (void)n_in; (void)out_size; (void)ws_size;
    unsigned short* wt = (unsigned short*)d_ws;   // 786432 B
    float* out = (float*)d_out;
    const int npts = in_sizes[0] / 3;

    wt_split_kernel<<<48, 256, 0, stream>>>(W1, W2, W3, wt);
    pinn_mfma<<<npts / NPTS_WG, 512, 0, stream>>>(x_norm, nu, x_std, y_std,
        W0, b0, b1, b2, b3, W4, wt, out);
}

// Round 16
// 146.546 us; speedup vs baseline: 1.2720x; 1.1736x over previous
//
#include <hip/hip_runtime.h>
#include <stdint.h>

typedef __attribute__((ext_vector_type(8))) _Float16 half8v;
typedef __attribute__((ext_vector_type(16))) float float16v;
typedef __attribute__((ext_vector_type(4))) float float4v;

#define NPTS_WG 32
#define NCH 5   // 0=value, 1-3=d1_i, 4=combined scaled Laplacian

// LDS act layout: [c][granule g = j>>3][p 32][8 u16]  (granule-major)
__device__ __forceinline__ int agp(int c, int g, int p) {
    return ((c * 32 + g) * 32 + p) * 8;
}

__device__ __forceinline__ unsigned short f16b(float x) {
    const _Float16 h = (_Float16)x;            // RN, 11-bit mantissa
    return __builtin_bit_cast(unsigned short, h);
}

__device__ __forceinline__ uint32_t pk2f16(float a, float b) {
    return (uint32_t)f16b(a) | ((uint32_t)f16b(b) << 16);
}

__device__ __forceinline__ float fast_tanh(float z) {
    const float e = __expf(2.0f * z);          // ~2 ulp
    return 1.0f - 2.0f / (e + 1.0f);           // exact saturation
}

// ---- precompute: W1..W3 -> fragment-order hi/lo f16 blocks in d_ws ----
// Block (L, part, wv, ch) = 64 lanes x 8 u16 (16B) = 1KB, contiguous.
// Lane l = hh*32 + l31 holds W[k = ch*16 + 8*hh + e][j = wv*32 + l31].
__global__ void wt_split_kernel(const float* __restrict__ W1, const float* __restrict__ W2,
                                const float* __restrict__ W3, unsigned short* __restrict__ wt)
{
    const int b = blockIdx.x;            // 48 blocks: 3 layers x 16 k-strips
    const int L = b >> 4;
    const int ch = b & 15;               // chunk = k>>4
    const int k0 = ch * 16;
    const float* W = (L == 0) ? W1 : (L == 1) ? W2 : W3;
    const int j = threadIdx.x;           // 0..255
    const int wv = j >> 5, l31 = j & 31;
    uint32_t hi[16], lo[16];
#pragma unroll
    for (int e = 0; e < 16; ++e) {
        const float x = W[(k0 + e) * 256 + j];     // coalesced: lanes = consecutive j
        const unsigned short h = f16b(x);
        const float hf = (float)__builtin_bit_cast(_Float16, h);
        hi[e] = h;
        lo[e] = f16b(x - hf);
    }
#pragma unroll
    for (int part = 0; part < 2; ++part) {
        const uint32_t* src = part ? lo : hi;
        unsigned short* base = wt +
            ((((size_t)(L * 2 + part) * 8 + wv) * 16 + ch) * 64) * 8;
#pragma unroll
        for (int hh = 0; hh < 2; ++hh) {
            uint4 v;
            const uint32_t* s = src + hh * 8;
            v.x = s[0] | (s[1] << 16);
            v.y = s[2] | (s[3] << 16);
            v.z = s[4] | (s[5] << 16);
            v.w = s[6] | (s[7] << 16);
            *(uint4*)(base + (hh * 32 + l31) * 8) = v;
        }
    }
}

// ---- main kernel: 512 threads (8 waves), 32 points/WG, 32x32x16 MFMA ----
__global__ __launch_bounds__(512, 2)
void pinn_mfma(const float* __restrict__ x_norm, const float* __restrict__ nu,
               const float* __restrict__ x_std, const float* __restrict__ y_std,
               const float* __restrict__ W0, const float* __restrict__ b0,
               const float* __restrict__ b1, const float* __restrict__ b2,
               const float* __restrict__ b3, const float* __restrict__ W4,
               const unsigned short* __restrict__ wt, float* __restrict__ out)
{
    __shared__ unsigned short AH[NCH * 32 * 256]; // 81920 B f16 activations
    __shared__ float w4_lds[256 * 4];             // 4 KB
    __shared__ float part_lds[8 * 4 * 32 * 4];    // 16 KB split-K partials
    __shared__ float y_lds[16 * 32];              // 2 KB

    const int tid = threadIdx.x;
    const int lane = tid & 63;
    const int wv = tid >> 6;     // wave 0..7
    const int l31 = lane & 31;
    const int hh = lane >> 5;    // 0..1 (k-half selector for 32x32 fragments)
    const int base_pt = blockIdx.x * NPTS_WG;

    const float xs0 = x_std[0], xs1 = x_std[1], xs2 = x_std[2];
    const float ixs20 = 1.f / (xs0 * xs0);
    const float ixs21 = 1.f / (xs1 * xs1);
    const float ixs22 = 1.f / (xs2 * xs2);

    if (tid < 256) ((float4*)w4_lds)[tid] = ((const float4*)W4)[tid];

    // ---- layer 0: 3 -> 256 dual seed (lap channel = sum of scaled d2 seeds) ----
    {
        const int p = tid & 31;            // 0..31 (varies per lane)
        const int jq = tid >> 5;           // 0..15
        const float x0 = x_norm[(base_pt + p) * 3 + 0];
        const float x1 = x_norm[(base_pt + p) * 3 + 1];
        const float x2 = x_norm[(base_pt + p) * 3 + 2];
#pragma unroll
        for (int hf = 0; hf < 2; ++hf) {
            const int j8 = jq * 16 + hf * 8;
            const int g = 2 * jq + hf;
            float w0r[8], w1r[8], w2r[8], b0r[8];
            *(float4*)&w0r[0] = *(const float4*)&W0[0 * 256 + j8];
            *(float4*)&w0r[4] = *(const float4*)&W0[0 * 256 + j8 + 4];
            *(float4*)&w1r[0] = *(const float4*)&W0[1 * 256 + j8];
            *(float4*)&w1r[4] = *(const float4*)&W0[1 * 256 + j8 + 4];
            *(float4*)&w2r[0] = *(const float4*)&W0[2 * 256 + j8];
            *(float4*)&w2r[4] = *(const float4*)&W0[2 * 256 + j8 + 4];
            *(float4*)&b0r[0] = *(const float4*)&b0[j8];
            *(float4*)&b0r[4] = *(const float4*)&b0[j8 + 4];
            union { unsigned short u[8]; half8v v; } hv[NCH];
#pragma unroll
            for (int e = 0; e < 8; ++e) {
                const float z = b0r[e] + x0 * w0r[e] + x1 * w1r[e] + x2 * w2r[e];
                const float t = fast_tanh(z);
                const float s = 1.f - t * t;
                hv[0].u[e] = f16b(t);
                hv[1].u[e] = f16b(s * w0r[e]);
                hv[2].u[e] = f16b(s * w1r[e]);
                hv[3].u[e] = f16b(s * w2r[e]);
                hv[4].u[e] = f16b(-2.f * t * s *
                    (w0r[e] * w0r[e] * ixs20 + w1r[e] * w1r[e] * ixs21 +
                     w2r[e] * w2r[e] * ixs22));
            }
#pragma unroll
            for (int c = 0; c < NCH; ++c)
                *(half8v*)&AH[agp(c, g, p)] = hv[c].v;  // stride-16B across lanes
        }
    }
    __syncthreads();

    // ---- layers 1..3: D[j' 32][p 32] = W x A via mfma_32x32x16 ----
    const float* biases[3] = {b1, b2, b3};
    const int laneq = lane * 8;

    // W fragment bases (1KB blocks, +512 u16 per chunk)
    const unsigned short* whb = wt + ((size_t)0 * 8 + wv) * 8192 + laneq;
    const unsigned short* wlb = wt + ((size_t)1 * 8 + wv) * 8192 + laneq;

    // prologue for L=0: W chunks 0,1; A chunks 0,1 (3-slot rolling, depth-2)
    half8v wh[3], wl[3], ab[3][NCH];
    wh[0] = *(const half8v*)(whb);
    wl[0] = *(const half8v*)(wlb);
    wh[1] = *(const half8v*)(whb + 512);
    wl[1] = *(const half8v*)(wlb + 512);
#pragma unroll
    for (int c = 0; c < NCH; ++c) {
        ab[0][c] = *(const half8v*)&AH[agp(c, hh, l31)];
        ab[1][c] = *(const half8v*)&AH[agp(c, 2 + hh, l31)];
    }

#pragma unroll 1
    for (int L = 0; L < 3; ++L) {
        const unsigned short* whL = wt + ((size_t)(L * 2 + 0) * 8 + wv) * 8192 + laneq;
        const unsigned short* wlL = wt + ((size_t)(L * 2 + 1) * 8 + wv) * 8192 + laneq;
        float16v acc[NCH];
#pragma unroll
        for (int c = 0; c < NCH; ++c)
#pragma unroll
            for (int e = 0; e < 16; ++e) acc[c][e] = 0.f;

#pragma unroll
        for (int ch = 0; ch < 16; ++ch) {
            if (ch < 14) {   // depth-2 prefetch: W (coalesced 1KB) + A (LDS)
                wh[(ch + 2) % 3] = *(const half8v*)(whL + (ch + 2) * 512);
                wl[(ch + 2) % 3] = *(const half8v*)(wlL + (ch + 2) * 512);
                const int ng = 2 * (ch + 2) + hh;
#pragma unroll
                for (int c = 0; c < NCH; ++c)
                    ab[(ch + 2) % 3][c] = *(const half8v*)&AH[agp(c, ng, l31)];
            }
            __builtin_amdgcn_s_setprio(1);
            // hi block (5 independent accs), then lo block (4) — no dep pairs
#pragma unroll
            for (int c = 0; c < NCH; ++c)
                acc[c] = __builtin_amdgcn_mfma_f32_32x32x16_f16(wh[ch % 3], ab[ch % 3][c], acc[c], 0, 0, 0);
#pragma unroll
            for (int c = 0; c < 4; ++c)   // lap (c=4): hi only (nu-damped)
                acc[c] = __builtin_amdgcn_mfma_f32_32x32x16_f16(wl[ch % 3], ab[ch % 3][c], acc[c], 0, 0, 0);
            __builtin_amdgcn_s_setprio(0);
        }

        // cross-layer W prefetch: flies during transform + barriers
        if (L < 2) {
            const unsigned short* whN = wt + ((size_t)((L + 1) * 2 + 0) * 8 + wv) * 8192 + laneq;
            const unsigned short* wlN = wt + ((size_t)((L + 1) * 2 + 1) * 8 + wv) * 8192 + laneq;
            wh[0] = *(const half8v*)(whN);
            wl[0] = *(const half8v*)(wlN);
            wh[1] = *(const half8v*)(whN + 512);
            wl[1] = *(const half8v*)(wlN + 512);
        }

        const float* bL = biases[L];
        __syncthreads();   // all reads of AH done before overwrite
        // D rows: j' = wv*32 + (reg&3) + 8*(reg>>2) + 4*hh, col p = l31
#pragma unroll
        for (int q = 0; q < 4; ++q) {
            const int j0 = wv * 32 + 8 * q + 4 * hh;   // 4-aligned row base
            const int g = wv * 4 + q;                  // granule of j0
            float bj[4];
            *(float4*)&bj[0] = *(const float4*)&bL[j0];
            float val[NCH][4];
#pragma unroll
            for (int r = 0; r < 4; ++r) {
                const int e = q * 4 + r;
                const float z = acc[0][e] + bj[r];
                const float t = fast_tanh(z);
                const float s = 1.f - t * t;
                const float d1a = acc[1][e], d1b = acc[2][e], d1c = acc[3][e];
                val[0][r] = t;
                val[1][r] = s * d1a;
                val[2][r] = s * d1b;
                val[3][r] = s * d1c;
                val[4][r] = s * acc[4][e] - 2.f * t * s *
                    (d1a * d1a * ixs20 + d1b * d1b * ixs21 + d1c * d1c * ixs22);
            }
#pragma unroll
            for (int c = 0; c < NCH; ++c) {
                const uint32_t u0 = pk2f16(val[c][0], val[c][1]);
                const uint32_t u1 = pk2f16(val[c][2], val[c][3]);
                *(uint2*)&AH[agp(c, g, l31) + 4 * hh] = make_uint2(u0, u1);
            }
        }
        __syncthreads();
        if (L < 2) {   // A prologue for next layer (after barrier)
#pragma unroll
            for (int c = 0; c < NCH; ++c) {
                ab[0][c] = *(const half8v*)&AH[agp(c, hh, l31)];
                ab[1][c] = *(const half8v*)&AH[agp(c, 2 + hh, l31)];
            }
        }
    }

    // ---- layer 4: 256 -> 4, split-K across 8 waves, 16x16x32, two p-halves ----
    // channels read: 1..3 (d1, hi+lo) and 4 (lap, hi only)
    {
        const int l15 = lane & 15;
        const int g4 = lane >> 4;
        const int koct = wv * 32 + 8 * g4;     // j index into act planes
        const int gr = wv * 4 + g4;            // its granule
        union { uint32_t u[4]; half8v v; } HB, LB;
#pragma unroll
        for (int i = 0; i < 4; ++i) {
            const float w0v = (l15 < 4) ? w4_lds[(koct + 2 * i) * 4 + l15] : 0.f;
            const float w1v = (l15 < 4) ? w4_lds[(koct + 2 * i + 1) * 4 + l15] : 0.f;
            const unsigned short h0 = f16b(w0v), h1 = f16b(w1v);
            const float r0 = w0v - (float)__builtin_bit_cast(_Float16, h0);
            const float r1 = w1v - (float)__builtin_bit_cast(_Float16, h1);
            HB.u[i] = (uint32_t)h0 | ((uint32_t)h1 << 16);
            LB.u[i] = (uint32_t)f16b(r0) | ((uint32_t)f16b(r1) << 16);
        }
        float4v acc4[4][2];
#pragma unroll
        for (int cc = 0; cc < 4; ++cc)
#pragma unroll
            for (int ph = 0; ph < 2; ++ph) acc4[cc][ph] = (float4v){0.f, 0.f, 0.f, 0.f};
#pragma unroll
        for (int cc = 0; cc < 4; ++cc) {
#pragma unroll
            for (int ph = 0; ph < 2; ++ph) {
                const half8v ah = *(const half8v*)&AH[agp(1 + cc, gr, l15 + 16 * ph)];
                acc4[cc][ph] = __builtin_amdgcn_mfma_f32_16x16x32_f16(HB.v, ah, acc4[cc][ph], 0, 0, 0);
                if (cc < 3)
                    acc4[cc][ph] = __builtin_amdgcn_mfma_f32_16x16x32_f16(LB.v, ah, acc4[cc][ph], 0, 0, 0);
            }
        }
        if (g4 == 0) {   // rows 0..3 = outputs u,v,w,p for point l15 + 16*ph
#pragma unroll
            for (int cc = 0; cc < 4; ++cc)
#pragma unroll
                for (int ph = 0; ph < 2; ++ph)
                    *(float4*)&part_lds[((wv * 4 + cc) * 32 + ph * 16 + l15) * 4] =
                        make_float4(acc4[cc][ph][0], acc4[cc][ph][1],
                                    acc4[cc][ph][2], acc4[cc][ph][3]);
        }
    }
    __syncthreads();

    {          // reduce split-K partials + de-normalization scale (16 x 32 items)
        const int p = tid & 31;
        const int co = tid >> 5;      // 0..15
        const int o = co & 3;
        const int c4 = co >> 2;       // 0-2 = d1_i, 3 = lap (pre-scaled by 1/xs^2)
        float sum = 0.f;
#pragma unroll
        for (int w8 = 0; w8 < 8; ++w8)
            sum += part_lds[((w8 * 4 + c4) * 32 + p) * 4 + o];
        const float scale = (c4 < 3) ? (y_std[o] / x_std[c4]) : y_std[o];
        y_lds[co * 32 + p] = sum * scale;
    }
    __syncthreads();

    if (tid < 32) {           // physics loss per point
        const int p = tid;
        const float nuv = nu[0];
        #define YV(c4, o) y_lds[(((c4) * 4) + (o)) * 32 + p]
        const float cont = YV(0, 0) + YV(1, 1) + YV(2, 2);
        const float mx = YV(0, 3) - nuv * YV(3, 0);
        const float my = YV(1, 3) - nuv * YV(3, 1);
        const float mz = YV(2, 3) - nuv * YV(3, 2);
        out[base_pt + p] = cont * cont + mx * mx + my * my + mz * mz;
        #undef YV
    }
}

extern "C" void kernel_launch(void* const* d_in, const int* in_sizes, int n_in,
                              void* d_out, int out_size, void* d_ws, size_t ws_size,
                              hipStream_t stream)
{
    const float* x_norm = (const float*)d_in[0];
    const float* nu     = (const float*)d_in[1];
    const float* x_std  = (const float*)d_in[2];
    const float* y_std  = (const float*)d_in[3];
    const float* W0 = (const float*)d_in[4];  const float* b0 = (const float*)d_in[5];
    const float* W1 = (const float*)d_in[6];  const float* b1 = (const float*)d_in[7];
    const float* W2 = (const float*)d_in[8];  const float* b2 = (const float*)d_in[9];
    const float* W3 = (const float*)d_in[10]; const float* b3 = (const float*)d_in[11];
    const float* W4 = (const float*)d_in[12];
    (void)n_in; (void)out_size; (void)ws_size;
    unsigned short* wt = (unsigned short*)d_ws;   // 786432 B
    float* out = (float*)d_out;
    const int npts = in_sizes[0] / 3;

    wt_split_kernel<<<48, 256, 0, stream>>>(W1, W2, W3, wt);
    pinn_mfma<<<npts / NPTS_WG, 512, 0, stream>>>(x_norm, nu, x_std, y_std,
        W0, b0, b1, b2, b3, W4, wt, out);
}

// Round 17
// 145.156 us; speedup vs baseline: 1.2841x; 1.0096x over previous
//
#include <hip/hip_runtime.h>
#include <stdint.h>

typedef __attribute__((ext_vector_type(8))) _Float16 half8v;
typedef __attribute__((ext_vector_type(16))) float float16v;
typedef __attribute__((ext_vector_type(4))) float float4v;

#define NPTS_WG 32
#define NCH 5   // 0=value, 1-3=d1_i, 4=combined scaled Laplacian

// LDS act layout: [c][granule g = j>>3][p 32][8 u16]  (granule-major)
__device__ __forceinline__ int agp(int c, int g, int p) {
    return ((c * 32 + g) * 32 + p) * 8;
}

__device__ __forceinline__ unsigned short f16b(float x) {
    const _Float16 h = (_Float16)x;            // RN, 11-bit mantissa
    return __builtin_bit_cast(unsigned short, h);
}

__device__ __forceinline__ uint32_t pk2f16(float a, float b) {
    return (uint32_t)f16b(a) | ((uint32_t)f16b(b) << 16);
}

__device__ __forceinline__ float fast_tanh(float z) {
    const float e = __expf(2.0f * z);          // ~2 ulp
    return 1.0f - 2.0f / (e + 1.0f);           // exact saturation
}

// ---- precompute: W1..W3 -> fragment-order hi/lo f16 blocks in d_ws ----
// Block (L, part, wv, ch) = 64 lanes x 8 u16 (16B) = 1KB, contiguous.
// Lane l = hh*32 + l31 holds W[k = ch*16 + 8*hh + e][j = wv*32 + l31].
__global__ void wt_split_kernel(const float* __restrict__ W1, const float* __restrict__ W2,
                                const float* __restrict__ W3, unsigned short* __restrict__ wt)
{
    const int b = blockIdx.x;            // 48 blocks: 3 layers x 16 k-strips
    const int L = b >> 4;
    const int ch = b & 15;               // chunk = k>>4
    const int k0 = ch * 16;
    const float* W = (L == 0) ? W1 : (L == 1) ? W2 : W3;
    const int j = threadIdx.x;           // 0..255
    const int wv = j >> 5, l31 = j & 31;
    uint32_t hi[16], lo[16];
#pragma unroll
    for (int e = 0; e < 16; ++e) {
        const float x = W[(k0 + e) * 256 + j];     // coalesced: lanes = consecutive j
        const unsigned short h = f16b(x);
        const float hf = (float)__builtin_bit_cast(_Float16, h);
        hi[e] = h;
        lo[e] = f16b(x - hf);
    }
#pragma unroll
    for (int part = 0; part < 2; ++part) {
        const uint32_t* src = part ? lo : hi;
        unsigned short* base = wt +
            ((((size_t)(L * 2 + part) * 8 + wv) * 16 + ch) * 64) * 8;
#pragma unroll
        for (int hh = 0; hh < 2; ++hh) {
            uint4 v;
            const uint32_t* s = src + hh * 8;
            v.x = s[0] | (s[1] << 16);
            v.y = s[2] | (s[3] << 16);
            v.z = s[4] | (s[5] << 16);
            v.w = s[6] | (s[7] << 16);
            *(uint4*)(base + (hh * 32 + l31) * 8) = v;
        }
    }
}

// ---- main kernel: 512 threads (8 waves), 32 points/WG, 32x32x16 MFMA ----
// launch_bounds(512,4): 128 regs/wave cap; LDS exactly 80KB -> 2 WG/CU,
// 4 waves/SIMD. TLP (not per-wave ILP) hides ds_read/L2 latency.
__global__ __launch_bounds__(512, 4)
void pinn_mfma(const float* __restrict__ x_norm, const float* __restrict__ nu,
               const float* __restrict__ x_std, const float* __restrict__ y_std,
               const float* __restrict__ W0, const float* __restrict__ b0,
               const float* __restrict__ b1, const float* __restrict__ b2,
               const float* __restrict__ b3, const float* __restrict__ W4,
               const unsigned short* __restrict__ wt, float* __restrict__ out)
{
    // 80 KB total. part_lds aliases AH channel 0 (dead during layer 4);
    // y_lds aliases AH channel 1 head (dead after layer-4 reads + barrier).
    __shared__ __align__(16) unsigned char smem[NCH * 32 * 256 * 2];
    unsigned short* AH = (unsigned short*)smem;
    float* part_lds = (float*)smem;               // 16 KB (= ch0 region)
    float* y_lds = (float*)(smem + 16384);        // 2 KB (ch1 region head)

    const int tid = threadIdx.x;
    const int lane = tid & 63;
    const int wv = tid >> 6;     // wave 0..7
    const int l31 = lane & 31;
    const int hh = lane >> 5;    // 0..1 (k-half selector for 32x32 fragments)
    const int base_pt = blockIdx.x * NPTS_WG;

    const float xs0 = x_std[0], xs1 = x_std[1], xs2 = x_std[2];
    const float ixs20 = 1.f / (xs0 * xs0);
    const float ixs21 = 1.f / (xs1 * xs1);
    const float ixs22 = 1.f / (xs2 * xs2);

    // ---- layer 0: 3 -> 256 dual seed (lap channel = sum of scaled d2 seeds) ----
    {
        const int p = tid & 31;            // 0..31 (varies per lane)
        const int jq = tid >> 5;           // 0..15
        const float x0 = x_norm[(base_pt + p) * 3 + 0];
        const float x1 = x_norm[(base_pt + p) * 3 + 1];
        const float x2 = x_norm[(base_pt + p) * 3 + 2];
#pragma unroll
        for (int hf = 0; hf < 2; ++hf) {
            const int j8 = jq * 16 + hf * 8;
            const int g = 2 * jq + hf;
            float w0r[8], w1r[8], w2r[8], b0r[8];
            *(float4*)&w0r[0] = *(const float4*)&W0[0 * 256 + j8];
            *(float4*)&w0r[4] = *(const float4*)&W0[0 * 256 + j8 + 4];
            *(float4*)&w1r[0] = *(const float4*)&W0[1 * 256 + j8];
            *(float4*)&w1r[4] = *(const float4*)&W0[1 * 256 + j8 + 4];
            *(float4*)&w2r[0] = *(const float4*)&W0[2 * 256 + j8];
            *(float4*)&w2r[4] = *(const float4*)&W0[2 * 256 + j8 + 4];
            *(float4*)&b0r[0] = *(const float4*)&b0[j8];
            *(float4*)&b0r[4] = *(const float4*)&b0[j8 + 4];
            union { unsigned short u[8]; half8v v; } hv[NCH];
#pragma unroll
            for (int e = 0; e < 8; ++e) {
                const float z = b0r[e] + x0 * w0r[e] + x1 * w1r[e] + x2 * w2r[e];
                const float t = fast_tanh(z);
                const float s = 1.f - t * t;
                hv[0].u[e] = f16b(t);
                hv[1].u[e] = f16b(s * w0r[e]);
                hv[2].u[e] = f16b(s * w1r[e]);
                hv[3].u[e] = f16b(s * w2r[e]);
                hv[4].u[e] = f16b(-2.f * t * s *
                    (w0r[e] * w0r[e] * ixs20 + w1r[e] * w1r[e] * ixs21 +
                     w2r[e] * w2r[e] * ixs22));
            }
#pragma unroll
            for (int c = 0; c < NCH; ++c)
                *(half8v*)&AH[agp(c, g, p)] = hv[c].v;  // stride-16B across lanes
        }
    }
    __syncthreads();

    // ---- layers 1..3: D[j' 32][p 32] = W x A via mfma_32x32x16 ----
    const float* biases[3] = {b1, b2, b3};
    const int laneq = lane * 8;

#pragma unroll 1
    for (int L = 0; L < 3; ++L) {
        const unsigned short* whL = wt + ((size_t)(L * 2 + 0) * 8 + wv) * 8192 + laneq;
        const unsigned short* wlL = wt + ((size_t)(L * 2 + 1) * 8 + wv) * 8192 + laneq;
        float16v acc[NCH];
#pragma unroll
        for (int c = 0; c < NCH; ++c)
#pragma unroll
            for (int e = 0; e < 16; ++e) acc[c][e] = 0.f;

        // W depth-1 double buffer; A read per chunk (TLP hides latency)
        half8v whA = *(const half8v*)(whL);
        half8v wlA = *(const half8v*)(wlL);
        half8v whB, wlB;

#pragma unroll
        for (int ch = 0; ch < 16; ++ch) {
            if (ch < 15) {   // W prefetch for ch+1 (coalesced 1KB block)
                if ((ch & 1) == 0) {
                    whB = *(const half8v*)(whL + (ch + 1) * 512);
                    wlB = *(const half8v*)(wlL + (ch + 1) * 512);
                } else {
                    whA = *(const half8v*)(whL + (ch + 1) * 512);
                    wlA = *(const half8v*)(wlL + (ch + 1) * 512);
                }
            }
            half8v a[NCH];
            const int g = 2 * ch + hh;
#pragma unroll
            for (int c = 0; c < NCH; ++c)
                a[c] = *(const half8v*)&AH[agp(c, g, l31)];
            const half8v wh = ((ch & 1) == 0) ? whA : whB;
            const half8v wl = ((ch & 1) == 0) ? wlA : wlB;
            __builtin_amdgcn_s_setprio(1);
#pragma unroll
            for (int c = 0; c < NCH; ++c)
                acc[c] = __builtin_amdgcn_mfma_f32_32x32x16_f16(wh, a[c], acc[c], 0, 0, 0);
#pragma unroll
            for (int c = 0; c < 4; ++c)   // lap (c=4): hi only (nu-damped)
                acc[c] = __builtin_amdgcn_mfma_f32_32x32x16_f16(wl, a[c], acc[c], 0, 0, 0);
            __builtin_amdgcn_s_setprio(0);
        }

        const float* bL = biases[L];
        __syncthreads();   // all reads of AH done before overwrite
        // D rows: j' = wv*32 + (reg&3) + 8*(reg>>2) + 4*hh, col p = l31
#pragma unroll
        for (int q = 0; q < 4; ++q) {
            const int j0 = wv * 32 + 8 * q + 4 * hh;   // 4-aligned row base
            const int g = wv * 4 + q;                  // granule of j0
            float bj[4];
            *(float4*)&bj[0] = *(const float4*)&bL[j0];
            float val[NCH][4];
#pragma unroll
            for (int r = 0; r < 4; ++r) {
                const int e = q * 4 + r;
                const float z = acc[0][e] + bj[r];
                const float t = fast_tanh(z);
                const float s = 1.f - t * t;
                const float d1a = acc[1][e], d1b = acc[2][e], d1c = acc[3][e];
                val[0][r] = t;
                val[1][r] = s * d1a;
                val[2][r] = s * d1b;
                val[3][r] = s * d1c;
                val[4][r] = s * acc[4][e] - 2.f * t * s *
                    (d1a * d1a * ixs20 + d1b * d1b * ixs21 + d1c * d1c * ixs22);
            }
#pragma unroll
            for (int c = 0; c < NCH; ++c) {
                const uint32_t u0 = pk2f16(val[c][0], val[c][1]);
                const uint32_t u1 = pk2f16(val[c][2], val[c][3]);
                *(uint2*)&AH[agp(c, g, l31) + 4 * hh] = make_uint2(u0, u1);
            }
        }
        __syncthreads();
    }

    // ---- layer 4: 256 -> 4, split-K across 8 waves, 16x16x32, two p-halves ----
    // channels read: 1..3 (d1, hi+lo) and 4 (lap, hi only). W4 direct from L2.
    {
        const int l15 = lane & 15;
        const int g4 = lane >> 4;
        const int koct = wv * 32 + 8 * g4;     // j index into act planes
        const int gr = wv * 4 + g4;            // its granule
        union { uint32_t u[4]; half8v v; } HB, LB;
#pragma unroll
        for (int i = 0; i < 4; ++i) {
            const float w0v = (l15 < 4) ? W4[(koct + 2 * i) * 4 + l15] : 0.f;
            const float w1v = (l15 < 4) ? W4[(koct + 2 * i + 1) * 4 + l15] : 0.f;
            const unsigned short h0 = f16b(w0v), h1 = f16b(w1v);
            const float r0 = w0v - (float)__builtin_bit_cast(_Float16, h0);
            const float r1 = w1v - (float)__builtin_bit_cast(_Float16, h1);
            HB.u[i] = (uint32_t)h0 | ((uint32_t)h1 << 16);
            LB.u[i] = (uint32_t)f16b(r0) | ((uint32_t)f16b(r1) << 16);
        }
        float4v acc4[4][2];
#pragma unroll
        for (int cc = 0; cc < 4; ++cc)
#pragma unroll
            for (int ph = 0; ph < 2; ++ph) acc4[cc][ph] = (float4v){0.f, 0.f, 0.f, 0.f};
#pragma unroll
        for (int cc = 0; cc < 4; ++cc) {
#pragma unroll
            for (int ph = 0; ph < 2; ++ph) {
                const half8v ah = *(const half8v*)&AH[agp(1 + cc, gr, l15 + 16 * ph)];
                acc4[cc][ph] = __builtin_amdgcn_mfma_f32_16x16x32_f16(HB.v, ah, acc4[cc][ph], 0, 0, 0);
                if (cc < 3)
                    acc4[cc][ph] = __builtin_amdgcn_mfma_f32_16x16x32_f16(LB.v, ah, acc4[cc][ph], 0, 0, 0);
            }
        }
        __syncthreads();   // all AH ch1..4 reads done before part_lds (ch0 alias) write
        if (g4 == 0) {     // rows 0..3 = outputs u,v,w,p for point l15 + 16*ph
#pragma unroll
            for (int cc = 0; cc < 4; ++cc)
#pragma unroll
                for (int ph = 0; ph < 2; ++ph)
                    *(float4*)&part_lds[((wv * 4 + cc) * 32 + ph * 16 + l15) * 4] =
                        make_float4(acc4[cc][ph][0], acc4[cc][ph][1],
                                    acc4[cc][ph][2], acc4[cc][ph][3]);
        }
    }
    __syncthreads();

    {          // reduce split-K partials + de-normalization scale (16 x 32 items)
        const int p = tid & 31;
        const int co = tid >> 5;      // 0..15
        const int o = co & 3;
        const int c4 = co >> 2;       // 0-2 = d1_i, 3 = lap (pre-scaled by 1/xs^2)
        float sum = 0.f;
#pragma unroll
        for (int w8 = 0; w8 < 8; ++w8)
            sum += part_lds[((w8 * 4 + c4) * 32 + p) * 4 + o];
        const float scale = (c4 < 3) ? (y_std[o] / x_std[c4]) : y_std[o];
        y_lds[co * 32 + p] = sum * scale;
    }
    __syncthreads();

    if (tid < 32) {           // physics loss per point
        const int p = tid;
        const float nuv = nu[0];
        #define YV(c4, o) y_lds[(((c4) * 4) + (o)) * 32 + p]
        const float cont = YV(0, 0) + YV(1, 1) + YV(2, 2);
        const float mx = YV(0, 3) - nuv * YV(3, 0);
        const float my = YV(1, 3) - nuv * YV(3, 1);
        const float mz = YV(2, 3) - nuv * YV(3, 2);
        out[base_pt + p] = cont * cont + mx * mx + my * my + mz * mz;
        #undef YV
    }
}

extern "C" void kernel_launch(void* const* d_in, const int* in_sizes, int n_in,
                              void* d_out, int out_size, void* d_ws, size_t ws_size,
                              hipStream_t stream)
{
    const float* x_norm = (const float*)d_in[0];
    const float* nu     = (const float*)d_in[1];
    const float* x_std  = (const float*)d_in[2];
    const float* y_std  = (const float*)d_in[3];
    const float* W0 = (const float*)d_in[4];  const float* b0 = (const float*)d_in[5];
    const float* W1 = (const float*)d_in[6];  const float* b1 = (const float*)d_in[7];
    const float* W2 = (const float*)d_in[8];  const float* b2 = (const float*)d_in[9];
    const float* W3 = (const float*)d_in[10]; const float* b3 = (const float*)d_in[11];
    const float* W4 = (const float*)d_in[12];
    (void)n_in; (void)out_size; (void)ws_size;
    unsigned short* wt = (unsigned short*)d_ws;   // 786432 B
    float* out = (float*)d_out;
    const int npts = in_sizes[0] / 3;

    wt_split_kernel<<<48, 256, 0, stream>>>(W1, W2, W3, wt);
    pinn_mfma<<<npts / NPTS_WG, 512, 0, stream>>>(x_norm, nu, x_std, y_std,
        W0, b0, b1, b2, b3, W4, wt, out);
}